// Round 1
// baseline (1247.143 us; speedup 1.0000x reference)
//
#include <hip/hip_runtime.h>
#include <hip/hip_fp16.h>
#include <stdint.h>

#define LT 512   // timesteps
#define NB 512   // batch
#define DI 128   // input dim
#define DH 128   // hidden dim
#define G4 512   // 4*H gates
#define MROWS (LT * NB)   // 262144 flat (t,n) rows

typedef _Float16 f16;
typedef __attribute__((ext_vector_type(2))) _Float16 f16x2;
typedef __attribute__((ext_vector_type(8))) _Float16 f16x8;
typedef __attribute__((ext_vector_type(4))) float floatx4;

__device__ __forceinline__ float dot2f(uint32_t a, uint32_t b, float c) {
#if __has_builtin(__builtin_amdgcn_fdot2)
    return __builtin_amdgcn_fdot2(__builtin_bit_cast(f16x2, a),
                                  __builtin_bit_cast(f16x2, b), c, false);
#else
    f16x2 pa = __builtin_bit_cast(f16x2, a);
    f16x2 pb = __builtin_bit_cast(f16x2, b);
    return c + (float)pa.x * (float)pb.x + (float)pa.y * (float)pb.y;
#endif
}

__device__ __forceinline__ uint32_t pack2(float x, float y) {
    f16x2 p;
    p.x = (_Float16)x;
    p.y = (_Float16)y;
    return __builtin_bit_cast(uint32_t, p);
}

__device__ __forceinline__ float sigm(float v) {
    return 1.f / (1.f + __expf(-v));
}

__device__ __forceinline__ float tanh_(float v) {
    float a = fabsf(v);
    float e = __expf(-2.f * a);
    float r = (1.f - e) / (1.f + e);
    return v < 0.f ? -r : r;
}

// ============================================================================
// Kernel 1: x-gates GEMM with bias baked in.
// Output layout: gx[row][j][gs] f16, j = hidden unit (0..127), gs = gate slice
// (0:i 1:f 2:g 3:o)  ->  one uint2 (f16x4) per (row, j), coalesced for kernel 2.
// Block = 512 thr = 8 waves, tile = 128 rows x ALL 512 gates. grid = MROWS/128.
// Wave w handles j in [w*16, w*16+16) for all 4 gate slices:
//   - A (x) staged once per tile (was twice with the gate-half split)
//   - stores are packed dwordx2 (was 64 scalar f16 stores/lane)
// ============================================================================
__launch_bounds__(512, 4)
__global__ void gemm_xgates(const float* __restrict__ x,
                            const float* __restrict__ Wih,
                            const float* __restrict__ bih,
                            const float* __restrict__ bhh,
                            f16* __restrict__ gx)
{
    __shared__ uint4 wx[128 * 16];   // 32 KB: 128 rows x 16 uint4 (8 f16 each)
    const int tid = threadIdx.x;
    const size_t rowbase = (size_t)blockIdx.x * 128;

    // ---- stage x-tile -> LDS as f16 frags (each thread: 128B contiguous) ----
    {
        const float4* src = (const float4*)(x + rowbase * DI) + (size_t)tid * 8;
#pragma unroll
        for (int i = 0; i < 4; ++i) {
            float4 a = src[2 * i];
            float4 b = src[2 * i + 1];
            uint4 u;
            u.x = pack2(a.x, a.y); u.y = pack2(a.z, a.w);
            u.z = pack2(b.x, b.y); u.w = pack2(b.z, b.w);
            int flat = tid * 4 + i;
            int row  = flat >> 4;
            int m    = flat & 15;
            wx[row * 16 + (m ^ (row & 15))] = u;
        }
    }

    const int lane = tid & 63;
    const int w    = tid >> 6;       // wave 0..7
    const int l16  = lane & 15;
    const int quad = lane >> 4;
    const int j    = w * 16 + l16;   // hidden unit 0..127

    // ---- B-frags: all 4 gate slices of column j (64 VGPRs) + bias ----
    f16x8 bfrag[4][4];
    float bs[4];
#pragma unroll
    for (int gs = 0; gs < 4; ++gs) {
        int gate = gs * 128 + j;
        bs[gs] = bih[gate] + bhh[gate];
        const float4* wp = (const float4*)(Wih + (size_t)gate * DI);
#pragma unroll
        for (int kc = 0; kc < 4; ++kc) {
            float4 a = wp[kc * 8 + quad * 2];
            float4 b = wp[kc * 8 + quad * 2 + 1];
            uint4 u;
            u.x = pack2(a.x, a.y); u.y = pack2(a.z, a.w);
            u.z = pack2(b.x, b.y); u.w = pack2(b.z, b.w);
            bfrag[gs][kc] = __builtin_bit_cast(f16x8, u);
        }
    }
    __syncthreads();

    // ---- 8 row-sets of 16: A from LDS, 16 MFMAs, packed f16x4 store ----
    uint2* gp = (uint2*)gx;
#pragma unroll
    for (int rs = 0; rs < 8; ++rs) {
        f16x8 afrag[4];
        int row = rs * 16 + l16;
#pragma unroll
        for (int kc = 0; kc < 4; ++kc) {
            int m = kc * 4 + quad;
            afrag[kc] = __builtin_bit_cast(f16x8, wx[row * 16 + (m ^ (row & 15))]);
        }
        floatx4 acc[4];
#pragma unroll
        for (int gs = 0; gs < 4; ++gs)
            acc[gs] = (floatx4){bs[gs], bs[gs], bs[gs], bs[gs]};   // bias baked in
#pragma unroll
        for (int kc = 0; kc < 4; ++kc) {
#pragma unroll
            for (int gs = 0; gs < 4; ++gs)
                acc[gs] = __builtin_amdgcn_mfma_f32_16x16x32_f16(
                    afrag[kc], bfrag[gs][kc], acc[gs], 0, 0, 0);
        }
        // C/D layout: col = lane&15 (=> gate col j), row = quad*4 + reg
        size_t orow = rowbase + (size_t)rs * 16 + quad * 4;
#pragma unroll
        for (int r = 0; r < 4; ++r) {
            uint2 u;
            u.x = pack2(acc[0][r], acc[1][r]);   // i, f
            u.y = pack2(acc[2][r], acc[3][r]);   // g, o
            gp[(orow + r) * 128 + j] = u;
        }
    }
}

// ============================================================================
// Kernel 2: recurrence, thread = hidden unit j (owns ALL 4 gates).
// 512 blocks x 128 threads (2 waves) = 2 blocks/CU at 1 wave/SIMD.
// Whh rows {j, 128+j, 256+j, 384+j} resident in 256 VGPRs.
// No gate exchange, no idle lanes, ONE barrier per step (double-buffered h).
// ============================================================================
__launch_bounds__(128, 1)
__global__ void lstm_rec(const f16* __restrict__ gx,     // [L*N][128][4] f16
                         const float* __restrict__ hc0,  // [N][2H]
                         const int*   __restrict__ isini,// [L][N]
                         const float* __restrict__ Whh,  // [4H][H]
                         float* __restrict__ out)        // [L][N][H] ++ [N][2H]
{
    const int j = threadIdx.x;   // hidden unit 0..127
    const int n = blockIdx.x;    // batch row

    __shared__ __align__(16) f16 sh_h[2][DH];   // double-buffered h
    __shared__ float sh_m[LT];                  // per-t mask, staged once

    // stage masks for this batch row (4 strided loads/thread, once)
    for (int t = j; t < LT; t += 128)
        sh_m[t] = 1.f - (float)isini[(size_t)t * NB + n];

    // Whh rows j, 128+j, 256+j, 384+j packed f16 -> 256 VGPRs, loop-resident
    uint32_t whh[4][64];
#pragma unroll
    for (int gs = 0; gs < 4; ++gs) {
        const float4* wp = (const float4*)(Whh + (size_t)(gs * 128 + j) * DH);
#pragma unroll
        for (int i = 0; i < 32; ++i) {
            float4 w4 = wp[i];
            whh[gs][2 * i]     = pack2(w4.x, w4.y);
            whh[gs][2 * i + 1] = pack2(w4.z, w4.w);
        }
    }

    float hval = hc0[(size_t)n * (2 * DH) + j];
    float cval = hc0[(size_t)n * (2 * DH) + DH + j];
    sh_h[0][j] = (f16)hval;

    const uint2* gxp = (const uint2*)gx + (size_t)n * DH + j;  // stride NB*DH/t
    uint2 gxv = gxp[0];                                        // t = 0 (bias baked in)
    __syncthreads();

    float* outp = out + (size_t)n * DH + j;

    for (int t = 0; t < LT; ++t) {
        // issue next-step prefetch first (hides global latency under dots)
        int tn = (t + 1 < LT) ? (t + 1) : t;
        uint2 gxn = gxp[(size_t)tn * (NB * DH)];
        const float m = sh_m[t];

        // ---- 4 gate dots: h (LDS broadcast) . whh rows, 256 fdot2, 8 chains ----
        const uint4* hp = (const uint4*)sh_h[t & 1];
        float acc[4][2];
#pragma unroll
        for (int gs = 0; gs < 4; ++gs) { acc[gs][0] = 0.f; acc[gs][1] = 0.f; }
#pragma unroll
        for (int i = 0; i < 8; ++i) {
            uint4 h0 = hp[2 * i];
            uint4 h1 = hp[2 * i + 1];
#pragma unroll
            for (int gs = 0; gs < 4; ++gs) {
                acc[gs][0] = dot2f(h0.x, whh[gs][8 * i + 0], acc[gs][0]);
                acc[gs][1] = dot2f(h0.y, whh[gs][8 * i + 1], acc[gs][1]);
                acc[gs][0] = dot2f(h0.z, whh[gs][8 * i + 2], acc[gs][0]);
                acc[gs][1] = dot2f(h0.w, whh[gs][8 * i + 3], acc[gs][1]);
                acc[gs][0] = dot2f(h1.x, whh[gs][8 * i + 4], acc[gs][0]);
                acc[gs][1] = dot2f(h1.y, whh[gs][8 * i + 5], acc[gs][1]);
                acc[gs][0] = dot2f(h1.z, whh[gs][8 * i + 6], acc[gs][0]);
                acc[gs][1] = dot2f(h1.w, whh[gs][8 * i + 7], acc[gs][1]);
            }
        }

        // ---- all gates local: no exchange, no idle lanes ----
        f16x2 p01 = __builtin_bit_cast(f16x2, gxv.x);
        f16x2 p23 = __builtin_bit_cast(f16x2, gxv.y);
        float ig = (float)p01.x + m * (acc[0][0] + acc[0][1]);
        float fg = (float)p01.y + m * (acc[1][0] + acc[1][1]);
        float gg = (float)p23.x + m * (acc[2][0] + acc[2][1]);
        float og = (float)p23.y + m * (acc[3][0] + acc[3][1]);
        float cc = sigm(fg) * (m * cval) + sigm(ig) * tanh_(gg);
        hval = sigm(og) * tanh_(cc);
        cval = cc;

        outp[(size_t)t * (NB * DH)] = hval;
        sh_h[(t + 1) & 1][j] = (f16)hval;    // write OTHER buffer
        gxv = gxn;
        __syncthreads();                     // single barrier per step
    }

    size_t base = (size_t)LT * NB * DH;
    out[base + (size_t)n * (2 * DH) + j]      = hval;
    out[base + (size_t)n * (2 * DH) + DH + j] = cval;
}

// ============================================================================
// Fallback (round-1 kernel, verified): used only if ws_size < 268 MB.
// ============================================================================
__launch_bounds__(512, 2)
__global__ void lstm_fused(const float* __restrict__ x,
                           const float* __restrict__ hc0,
                           const int*   __restrict__ isini,
                           const float* __restrict__ Wih,
                           const float* __restrict__ Whh,
                           const float* __restrict__ bih,
                           const float* __restrict__ bhh,
                           float* __restrict__ out)
{
    const int g   = threadIdx.x;
    const int n0  = blockIdx.x * 2;

    __shared__ __align__(16) f16   sh_h[2][DH];
    __shared__ __align__(16) f16   sh_x[2][2][DI];
    __shared__ __align__(16) float sh_gates[2][G4];

    uint32_t wih[64], whh[64];
    {
        const float4* wi = (const float4*)(Wih + (size_t)g * DI);
        const float4* wh = (const float4*)(Whh + (size_t)g * DI);
#pragma unroll
        for (int i = 0; i < 32; ++i) {
            float4 a = wi[i];
            wih[2 * i]     = pack2(a.x, a.y);
            wih[2 * i + 1] = pack2(a.z, a.w);
            float4 b = wh[i];
            whh[2 * i]     = pack2(b.x, b.y);
            whh[2 * i + 1] = pack2(b.z, b.w);
        }
    }
    const float bias = bih[g] + bhh[g];
    const int row = (threadIdx.x >> 7) & 1;
    const int j   = threadIdx.x & 127;
    const int n   = n0 + row;

    float cval = 0.f, hval = 0.f;

    if (threadIdx.x < 256) {
        cval = hc0[(size_t)n * (2 * DH) + DH + j];
        float h0 = hc0[(size_t)n * (2 * DH) + j];
        sh_h[row][j] = (f16)h0;
    } else {
        float xv0 = x[((size_t)0 * NB + n) * DI + j];
        sh_x[0][row][j] = (f16)xv0;
    }
    __syncthreads();

    for (int t = 0; t < LT; ++t) {
        const float m0 = 1.f - (float)isini[(size_t)t * NB + n0];
        const float m1 = 1.f - (float)isini[(size_t)t * NB + n0 + 1];

        float xpre = 0.f;
        if (threadIdx.x >= 256) {
            int tp = (t + 1 < LT) ? (t + 1) : (LT - 1);
            xpre = x[((size_t)tp * NB + n) * DI + j];
        }

        const uint4* xp0 = (const uint4*)&sh_x[t & 1][0][0];
        const uint4* xp1 = (const uint4*)&sh_x[t & 1][1][0];
        const uint4* hp0 = (const uint4*)&sh_h[0][0];
        const uint4* hp1 = (const uint4*)&sh_h[1][0];

        float ax0 = 0.f, ax0b = 0.f, ah0 = 0.f, ah0b = 0.f;
        float ax1 = 0.f, ax1b = 0.f, ah1 = 0.f, ah1b = 0.f;
#pragma unroll
        for (int i = 0; i < 16; ++i) {
            uint4 xv0 = xp0[i];
            uint4 xv1 = xp1[i];
            uint4 hv0 = hp0[i];
            uint4 hv1 = hp1[i];
            ax0  = dot2f(xv0.x, wih[4 * i + 0], ax0);
            ax0b = dot2f(xv0.y, wih[4 * i + 1], ax0b);
            ax0  = dot2f(xv0.z, wih[4 * i + 2], ax0);
            ax0b = dot2f(xv0.w, wih[4 * i + 3], ax0b);
            ah0  = dot2f(hv0.x, whh[4 * i + 0], ah0);
            ah0b = dot2f(hv0.y, whh[4 * i + 1], ah0b);
            ah0  = dot2f(hv0.z, whh[4 * i + 2], ah0);
            ah0b = dot2f(hv0.w, whh[4 * i + 3], ah0b);
            ax1  = dot2f(xv1.x, wih[4 * i + 0], ax1);
            ax1b = dot2f(xv1.y, wih[4 * i + 1], ax1b);
            ax1  = dot2f(xv1.z, wih[4 * i + 2], ax1);
            ax1b = dot2f(xv1.w, wih[4 * i + 3], ax1b);
            ah1  = dot2f(hv1.x, whh[4 * i + 0], ah1);
            ah1b = dot2f(hv1.y, whh[4 * i + 1], ah1b);
            ah1  = dot2f(hv1.z, whh[4 * i + 2], ah1);
            ah1b = dot2f(hv1.w, whh[4 * i + 3], ah1b);
        }
        sh_gates[0][g] = bias + (ax0 + ax0b) + m0 * (ah0 + ah0b);
        sh_gates[1][g] = bias + (ax1 + ax1b) + m1 * (ah1 + ah1b);

        __syncthreads();

        if (threadIdx.x < 256) {
            float ig = sh_gates[row][j];
            float fg = sh_gates[row][128 + j];
            float gg = sh_gates[row][256 + j];
            float og = sh_gates[row][384 + j];
            float m  = row ? m1 : m0;
            float cc = m * cval;
            cc   = sigm(fg) * cc + sigm(ig) * tanh_(gg);
            hval = sigm(og) * tanh_(cc);
            cval = cc;
            out[((size_t)t * NB + n) * DH + j] = hval;
            sh_h[row][j] = (f16)hval;
        } else {
            sh_x[(t + 1) & 1][row][j] = (f16)xpre;
        }
        __syncthreads();
    }

    if (threadIdx.x < 256) {
        size_t base = (size_t)LT * NB * DH;
        out[base + (size_t)n * (2 * DH) + j]      = hval;
        out[base + (size_t)n * (2 * DH) + DH + j] = cval;
    }
}

extern "C" void kernel_launch(void* const* d_in, const int* in_sizes, int n_in,
                              void* d_out, int out_size, void* d_ws, size_t ws_size,
                              hipStream_t stream) {
    const float* x     = (const float*)d_in[0];
    const float* hc0   = (const float*)d_in[1];
    const int*   isini = (const int*)d_in[2];
    const float* Wih   = (const float*)d_in[3];
    const float* Whh   = (const float*)d_in[4];
    const float* bih   = (const float*)d_in[5];
    const float* bhh   = (const float*)d_in[6];
    float* out = (float*)d_out;

    const size_t need = (size_t)MROWS * G4 * sizeof(f16);   // 268 MB
    if (ws_size >= need) {
        f16* gx = (f16*)d_ws;
        gemm_xgates<<<dim3(MROWS / 128), dim3(512), 0, stream>>>(x, Wih, bih, bhh, gx);
        lstm_rec<<<dim3(NB), dim3(128), 0, stream>>>(gx, hc0, isini, Whh, out);
    } else {
        lstm_fused<<<dim3(NB / 2), dim3(512), 0, stream>>>(
            x, hc0, isini, Wih, Whh, bih, bhh, out);
    }
}

// Round 2
// 667.263 us; speedup vs baseline: 1.8690x; 1.8690x over previous
//
#include <hip/hip_runtime.h>
#include <hip/hip_fp16.h>
#include <stdint.h>

#define LT 512   // timesteps
#define NB 512   // batch
#define DI 128   // input dim
#define DH 128   // hidden dim
#define G4 512   // 4*H gates
#define MROWS (LT * NB)   // 262144 flat (t,n) rows

typedef _Float16 f16;
typedef __attribute__((ext_vector_type(2))) _Float16 f16x2;
typedef __attribute__((ext_vector_type(8))) _Float16 f16x8;
typedef __attribute__((ext_vector_type(4))) float floatx4;

__device__ __forceinline__ float dot2f(uint32_t a, uint32_t b, float c) {
#if __has_builtin(__builtin_amdgcn_fdot2)
    return __builtin_amdgcn_fdot2(__builtin_bit_cast(f16x2, a),
                                  __builtin_bit_cast(f16x2, b), c, false);
#else
    f16x2 pa = __builtin_bit_cast(f16x2, a);
    f16x2 pb = __builtin_bit_cast(f16x2, b);
    return c + (float)pa.x * (float)pb.x + (float)pa.y * (float)pb.y;
#endif
}

__device__ __forceinline__ uint32_t pack2(float x, float y) {
    f16x2 p;
    p.x = (_Float16)x;
    p.y = (_Float16)y;
    return __builtin_bit_cast(uint32_t, p);
}

__device__ __forceinline__ float sigm(float v) {
    return 1.f / (1.f + __expf(-v));
}

__device__ __forceinline__ float tanh_(float v) {
    float a = fabsf(v);
    float e = __expf(-2.f * a);
    float r = (1.f - e) / (1.f + e);
    return v < 0.f ? -r : r;
}

// ============================================================================
// Kernel 1: x-gates GEMM with bias baked in.  (unchanged from round 1)
// Output layout: gx[row][j] = uint2 { pack2(i,f), pack2(g,o) }, j = hidden unit.
// ============================================================================
__launch_bounds__(512, 4)
__global__ void gemm_xgates(const float* __restrict__ x,
                            const float* __restrict__ Wih,
                            const float* __restrict__ bih,
                            const float* __restrict__ bhh,
                            f16* __restrict__ gx)
{
    __shared__ uint4 wx[128 * 16];   // 32 KB: 128 rows x 16 uint4 (8 f16 each)
    const int tid = threadIdx.x;
    const size_t rowbase = (size_t)blockIdx.x * 128;

    // ---- stage x-tile -> LDS as f16 frags (each thread: 128B contiguous) ----
    {
        const float4* src = (const float4*)(x + rowbase * DI) + (size_t)tid * 8;
#pragma unroll
        for (int i = 0; i < 4; ++i) {
            float4 a = src[2 * i];
            float4 b = src[2 * i + 1];
            uint4 u;
            u.x = pack2(a.x, a.y); u.y = pack2(a.z, a.w);
            u.z = pack2(b.x, b.y); u.w = pack2(b.z, b.w);
            int flat = tid * 4 + i;
            int row  = flat >> 4;
            int m    = flat & 15;
            wx[row * 16 + (m ^ (row & 15))] = u;
        }
    }

    const int lane = tid & 63;
    const int w    = tid >> 6;       // wave 0..7
    const int l16  = lane & 15;
    const int quad = lane >> 4;
    const int j    = w * 16 + l16;   // hidden unit 0..127

    // ---- B-frags: all 4 gate slices of column j (64 VGPRs) + bias ----
    f16x8 bfrag[4][4];
    float bs[4];
#pragma unroll
    for (int gs = 0; gs < 4; ++gs) {
        int gate = gs * 128 + j;
        bs[gs] = bih[gate] + bhh[gate];
        const float4* wp = (const float4*)(Wih + (size_t)gate * DI);
#pragma unroll
        for (int kc = 0; kc < 4; ++kc) {
            float4 a = wp[kc * 8 + quad * 2];
            float4 b = wp[kc * 8 + quad * 2 + 1];
            uint4 u;
            u.x = pack2(a.x, a.y); u.y = pack2(a.z, a.w);
            u.z = pack2(b.x, b.y); u.w = pack2(b.z, b.w);
            bfrag[gs][kc] = __builtin_bit_cast(f16x8, u);
        }
    }
    __syncthreads();

    // ---- 8 row-sets of 16: A from LDS, 16 MFMAs, packed f16x4 store ----
    uint2* gp = (uint2*)gx;
#pragma unroll
    for (int rs = 0; rs < 8; ++rs) {
        f16x8 afrag[4];
        int row = rs * 16 + l16;
#pragma unroll
        for (int kc = 0; kc < 4; ++kc) {
            int m = kc * 4 + quad;
            afrag[kc] = __builtin_bit_cast(f16x8, wx[row * 16 + (m ^ (row & 15))]);
        }
        floatx4 acc[4];
#pragma unroll
        for (int gs = 0; gs < 4; ++gs)
            acc[gs] = (floatx4){bs[gs], bs[gs], bs[gs], bs[gs]};   // bias baked in
#pragma unroll
        for (int kc = 0; kc < 4; ++kc) {
#pragma unroll
            for (int gs = 0; gs < 4; ++gs)
                acc[gs] = __builtin_amdgcn_mfma_f32_16x16x32_f16(
                    afrag[kc], bfrag[gs][kc], acc[gs], 0, 0, 0);
        }
        // C/D layout: col = lane&15 (=> gate col j), row = quad*4 + reg
        size_t orow = rowbase + (size_t)rs * 16 + quad * 4;
#pragma unroll
        for (int r = 0; r < 4; ++r) {
            uint2 u;
            u.x = pack2(acc[0][r], acc[1][r]);   // i, f
            u.y = pack2(acc[2][r], acc[3][r]);   // g, o
            gp[(orow + r) * 128 + j] = u;
        }
    }
}

// ============================================================================
// Kernel 2: recurrence via MFMA. 256 blocks (1/CU) x 512 thr (8 waves).
// Block owns batch rows n0 = 2*blockIdx, n0+1.
// Per step: A = h replicated (M rows 0-7 <- n0, 8-15 <- n1) from LDS;
// B = Whh frags, REGISTER-RESIDENT at 64 VGPRs/thread (f16-packed).
// Wave w covers unit group j = w*16 + l16 for all 4 gate slices ->
// lanes quad0 (n0) / quad2 (n1) hold all 4 gates of unit j in acc[gs][0]:
// nonlinearity fully lane-local, 1 barrier/step, double-buffered h.
// ============================================================================
__launch_bounds__(512, 2)
__global__ void lstm_rec_mfma(const f16* __restrict__ gx,     // [L*N][128] uint2
                              const float* __restrict__ hc0,  // [N][2H]
                              const int*   __restrict__ isini,// [L][N]
                              const float* __restrict__ Whh,  // [4H][H]
                              float* __restrict__ out)        // [L][N][H] ++ [N][2H]
{
    const int tid  = threadIdx.x;
    const int lane = tid & 63;
    const int w    = tid >> 6;       // wave 0..7
    const int l16  = lane & 15;
    const int quad = lane >> 4;
    const int n0   = blockIdx.x * 2;
    const int j    = w * 16 + l16;   // hidden unit 0..127

    __shared__ __align__(16) f16 sh_h[2][2][DH];   // [buf][row][j], 1 KB
    __shared__ float sh_m[2][LT];                  // masks, 4 KB

    // ---- stage masks (one element per thread) ----
    for (int t = tid; t < LT; t += 512) {
        sh_m[0][t] = 1.f - (float)isini[(size_t)t * NB + n0];
        sh_m[1][t] = 1.f - (float)isini[(size_t)t * NB + n0 + 1];
    }

    // ---- B-frags: Whh rows gate = gs*128 + j, packed f16 (64 VGPRs) ----
    f16x8 bfrag[4][4];
#pragma unroll
    for (int gs = 0; gs < 4; ++gs) {
        const float4* wp = (const float4*)(Whh + (size_t)(gs * 128 + j) * DH);
#pragma unroll
        for (int kc = 0; kc < 4; ++kc) {
            float4 a = wp[kc * 8 + quad * 2];
            float4 b = wp[kc * 8 + quad * 2 + 1];
            uint4 u;
            u.x = pack2(a.x, a.y); u.y = pack2(a.z, a.w);
            u.z = pack2(b.x, b.y); u.w = pack2(b.z, b.w);
            bfrag[gs][kc] = __builtin_bit_cast(f16x8, u);
        }
    }

    // active lanes: quad 0 -> n0, quad 2 -> n1 (C rows m=0..3 / m=8..11, reg 0)
    const bool act = (quad & 1) == 0;
    const int  nr  = quad >> 1;           // 0 or 1
    const int  n   = n0 + nr;

    float cval = 0.f, hval = 0.f;
    if (act) {
        hval = hc0[(size_t)n * (2 * DH) + j];
        cval = hc0[(size_t)n * (2 * DH) + DH + j];
        sh_h[0][nr][j] = (f16)hval;
    }

    const uint2* gxp = (const uint2*)gx;
    uint2 gxv = make_uint2(0u, 0u);
    if (act) gxv = gxp[(size_t)n * DH + j];   // t = 0 (bias baked in)
    __syncthreads();

    const int rowsel = l16 >> 3;   // A rows 0-7 <- n0, 8-15 <- n1
    float* outp = out + (size_t)n * DH + j;

    for (int t = 0; t < LT; ++t) {
        const int buf = t & 1;

        // prefetch next-step gx early (hidden under MFMA + nonlin)
        int tn = (t + 1 < LT) ? (t + 1) : t;
        uint2 gxn = make_uint2(0u, 0u);
        if (act) gxn = gxp[((size_t)tn * NB + n) * DH + j];

        // ---- A-frags from LDS (broadcast, 2-way banks = free) + 16 MFMA ----
        const uint4* hb = (const uint4*)&sh_h[buf][0][0];
        floatx4 acc[4];
#pragma unroll
        for (int gs = 0; gs < 4; ++gs) acc[gs] = (floatx4){0.f, 0.f, 0.f, 0.f};
#pragma unroll
        for (int kc = 0; kc < 4; ++kc) {
            f16x8 af = __builtin_bit_cast(f16x8, hb[rowsel * 16 + kc * 4 + quad]);
#pragma unroll
            for (int gs = 0; gs < 4; ++gs)
                acc[gs] = __builtin_amdgcn_mfma_f32_16x16x32_f16(
                    af, bfrag[gs][kc], acc[gs], 0, 0, 0);
        }

        // ---- lane-local gate combine + nonlinearity (quads 0,2) ----
        if (act) {
            const float m = sh_m[nr][t];
            f16x2 p01 = __builtin_bit_cast(f16x2, gxv.x);
            f16x2 p23 = __builtin_bit_cast(f16x2, gxv.y);
            float ig = (float)p01.x + m * acc[0][0];
            float fg = (float)p01.y + m * acc[1][0];
            float gg = (float)p23.x + m * acc[2][0];
            float og = (float)p23.y + m * acc[3][0];
            float cc = sigm(fg) * (m * cval) + sigm(ig) * tanh_(gg);
            hval = sigm(og) * tanh_(cc);
            cval = cc;
            outp[(size_t)t * (NB * DH)] = hval;
            sh_h[buf ^ 1][nr][j] = (f16)hval;    // write OTHER buffer
        }
        gxv = gxn;
        __syncthreads();                          // single barrier per step
    }

    if (act) {
        size_t base = (size_t)LT * NB * DH;
        out[base + (size_t)n * (2 * DH) + j]      = hval;
        out[base + (size_t)n * (2 * DH) + DH + j] = cval;
    }
}

// ============================================================================
// Fallback (round-1 kernel, verified): used only if ws_size < 268 MB.
// ============================================================================
__launch_bounds__(512, 2)
__global__ void lstm_fused(const float* __restrict__ x,
                           const float* __restrict__ hc0,
                           const int*   __restrict__ isini,
                           const float* __restrict__ Wih,
                           const float* __restrict__ Whh,
                           const float* __restrict__ bih,
                           const float* __restrict__ bhh,
                           float* __restrict__ out)
{
    const int g   = threadIdx.x;
    const int n0  = blockIdx.x * 2;

    __shared__ __align__(16) f16   sh_h[2][DH];
    __shared__ __align__(16) f16   sh_x[2][2][DI];
    __shared__ __align__(16) float sh_gates[2][G4];

    uint32_t wih[64], whh[64];
    {
        const float4* wi = (const float4*)(Wih + (size_t)g * DI);
        const float4* wh = (const float4*)(Whh + (size_t)g * DI);
#pragma unroll
        for (int i = 0; i < 32; ++i) {
            float4 a = wi[i];
            wih[2 * i]     = pack2(a.x, a.y);
            wih[2 * i + 1] = pack2(a.z, a.w);
            float4 b = wh[i];
            whh[2 * i]     = pack2(b.x, b.y);
            whh[2 * i + 1] = pack2(b.z, b.w);
        }
    }
    const float bias = bih[g] + bhh[g];
    const int row = (threadIdx.x >> 7) & 1;
    const int j   = threadIdx.x & 127;
    const int n   = n0 + row;

    float cval = 0.f, hval = 0.f;

    if (threadIdx.x < 256) {
        cval = hc0[(size_t)n * (2 * DH) + DH + j];
        float h0 = hc0[(size_t)n * (2 * DH) + j];
        sh_h[row][j] = (f16)h0;
    } else {
        float xv0 = x[((size_t)0 * NB + n) * DI + j];
        sh_x[0][row][j] = (f16)xv0;
    }
    __syncthreads();

    for (int t = 0; t < LT; ++t) {
        const float m0 = 1.f - (float)isini[(size_t)t * NB + n0];
        const float m1 = 1.f - (float)isini[(size_t)t * NB + n0 + 1];

        float xpre = 0.f;
        if (threadIdx.x >= 256) {
            int tp = (t + 1 < LT) ? (t + 1) : (LT - 1);
            xpre = x[((size_t)tp * NB + n) * DI + j];
        }

        const uint4* xp0 = (const uint4*)&sh_x[t & 1][0][0];
        const uint4* xp1 = (const uint4*)&sh_x[t & 1][1][0];
        const uint4* hp0 = (const uint4*)&sh_h[0][0];
        const uint4* hp1 = (const uint4*)&sh_h[1][0];

        float ax0 = 0.f, ax0b = 0.f, ah0 = 0.f, ah0b = 0.f;
        float ax1 = 0.f, ax1b = 0.f, ah1 = 0.f, ah1b = 0.f;
#pragma unroll
        for (int i = 0; i < 16; ++i) {
            uint4 xv0 = xp0[i];
            uint4 xv1 = xp1[i];
            uint4 hv0 = hp0[i];
            uint4 hv1 = hp1[i];
            ax0  = dot2f(xv0.x, wih[4 * i + 0], ax0);
            ax0b = dot2f(xv0.y, wih[4 * i + 1], ax0b);
            ax0  = dot2f(xv0.z, wih[4 * i + 2], ax0);
            ax0b = dot2f(xv0.w, wih[4 * i + 3], ax0b);
            ah0  = dot2f(hv0.x, whh[4 * i + 0], ah0);
            ah0b = dot2f(hv0.y, whh[4 * i + 1], ah0b);
            ah0  = dot2f(hv0.z, whh[4 * i + 2], ah0);
            ah0b = dot2f(hv0.w, whh[4 * i + 3], ah0b);
            ax1  = dot2f(xv1.x, wih[4 * i + 0], ax1);
            ax1b = dot2f(xv1.y, wih[4 * i + 1], ax1b);
            ax1  = dot2f(xv1.z, wih[4 * i + 2], ax1);
            ax1b = dot2f(xv1.w, wih[4 * i + 3], ax1b);
            ah1  = dot2f(hv1.x, whh[4 * i + 0], ah1);
            ah1b = dot2f(hv1.y, whh[4 * i + 1], ah1b);
            ah1  = dot2f(hv1.z, whh[4 * i + 2], ah1);
            ah1b = dot2f(hv1.w, whh[4 * i + 3], ah1b);
        }
        sh_gates[0][g] = bias + (ax0 + ax0b) + m0 * (ah0 + ah0b);
        sh_gates[1][g] = bias + (ax1 + ax1b) + m1 * (ah1 + ah1b);

        __syncthreads();

        if (threadIdx.x < 256) {
            float ig = sh_gates[row][j];
            float fg = sh_gates[row][128 + j];
            float gg = sh_gates[row][256 + j];
            float og = sh_gates[row][384 + j];
            float m  = row ? m1 : m0;
            float cc = m * cval;
            cc   = sigm(fg) * cc + sigm(ig) * tanh_(gg);
            hval = sigm(og) * tanh_(cc);
            cval = cc;
            out[((size_t)t * NB + n) * DH + j] = hval;
            sh_h[row][j] = (f16)hval;
        } else {
            sh_x[(t + 1) & 1][row][j] = (f16)xpre;
        }
        __syncthreads();
    }

    if (threadIdx.x < 256) {
        size_t base = (size_t)LT * NB * DH;
        out[base + (size_t)n * (2 * DH) + j]      = hval;
        out[base + (size_t)n * (2 * DH) + DH + j] = cval;
    }
}

extern "C" void kernel_launch(void* const* d_in, const int* in_sizes, int n_in,
                              void* d_out, int out_size, void* d_ws, size_t ws_size,
                              hipStream_t stream) {
    const float* x     = (const float*)d_in[0];
    const float* hc0   = (const float*)d_in[1];
    const int*   isini = (const int*)d_in[2];
    const float* Wih   = (const float*)d_in[3];
    const float* Whh   = (const float*)d_in[4];
    const float* bih   = (const float*)d_in[5];
    const float* bhh   = (const float*)d_in[6];
    float* out = (float*)d_out;

    const size_t need = (size_t)MROWS * G4 * sizeof(f16);   // 268 MB
    if (ws_size >= need) {
        f16* gx = (f16*)d_ws;
        gemm_xgates<<<dim3(MROWS / 128), dim3(512), 0, stream>>>(x, Wih, bih, bhh, gx);
        lstm_rec_mfma<<<dim3(NB / 2), dim3(512), 0, stream>>>(gx, hc0, isini, Whh, out);
    } else {
        lstm_fused<<<dim3(NB / 2), dim3(512), 0, stream>>>(
            x, hc0, isini, Wih, Whh, bih, bhh, out);
    }
}

// Round 3
// 590.515 us; speedup vs baseline: 2.1120x; 1.1300x over previous
//
#include <hip/hip_runtime.h>
#include <hip/hip_fp16.h>
#include <stdint.h>

#define LT 512   // timesteps
#define NB 512   // batch
#define DI 128   // input dim
#define DH 128   // hidden dim
#define AROW 272 // A-row stride in f16 (256 K + 16 pad -> rows 8 banks apart)
#define ASTR 34  // A-row stride in uint4

typedef _Float16 f16;
typedef __attribute__((ext_vector_type(2))) _Float16 f16x2;
typedef __attribute__((ext_vector_type(8))) _Float16 f16x8;
typedef __attribute__((ext_vector_type(4))) float floatx4;

// RTN f16 pack (keep numerics identical to verified rounds; no pkrtz)
__device__ __forceinline__ uint32_t pack2(float x, float y) {
    f16x2 p;
    p.x = (_Float16)x;
    p.y = (_Float16)y;
    return __builtin_bit_cast(uint32_t, p);
}

__device__ __forceinline__ float frcp(float x) {
#if __has_builtin(__builtin_amdgcn_rcpf)
    return __builtin_amdgcn_rcpf(x);   // v_rcp_f32, ~1ulp — absmax budget is 0.0078
#else
    return 1.f / x;
#endif
}

__device__ __forceinline__ float sigm(float v) {
    return frcp(1.f + __expf(-v));
}

__device__ __forceinline__ float tanh_(float v) {
    float a = fabsf(v);
    float e = __expf(-2.f * a);
    float r = (1.f - e) * frcp(1.f + e);
    return v < 0.f ? -r : r;
}

// ============================================================================
// Fully fused LSTM: one kernel, no workspace.
// 256 blocks (1/CU) x 512 thr (8 waves). Block owns batch rows n0, n0+1.
// gates(t) = [x(t) | h(t-1)*m(t)] . [Wih | Whh]^T + b   via K=256 MFMA chain.
//   A: 16 M-rows = 8 replicas each of the 2 batch rows, staged f16 in LDS
//      (x part k=0..127 prefetched 2 steps deep; h part k=128..255 written
//       masked at the end of the previous step)  -> mask folds into A.
//   B: [Wih|Whh] f16 frags REGISTER-RESIDENT, 128 VGPRs/thread.
// Wave w covers units j = w*16+l16, all 4 gate slices -> lanes quad0 (n0) /
// quad2 (n1) hold all 4 gates of unit j in acc[gs][0]: nonlinearity is
// lane-local, 1 barrier/step.
// vs round 2: deletes the 257 us gemm kernel + 536 MB gx HBM round-trip;
// approx-rcp nonlinearity; padded A rows (8-bank row offset).
// ============================================================================
__launch_bounds__(512, 2)
__global__ void lstm_fused_mfma(const float* __restrict__ x,
                                const float* __restrict__ hc0,
                                const int*   __restrict__ isini,
                                const float* __restrict__ Wih,
                                const float* __restrict__ Whh,
                                const float* __restrict__ bih,
                                const float* __restrict__ bhh,
                                float* __restrict__ out)
{
    const int tid  = threadIdx.x;
    const int lane = tid & 63;
    const int w    = tid >> 6;       // wave 0..7
    const int l16  = lane & 15;
    const int quad = lane >> 4;
    const int n0   = blockIdx.x * 2;
    const int j    = w * 16 + l16;   // hidden unit 0..127

    __shared__ __align__(16) f16 sh_a[2][2][AROW];  // [buf][row][k] (~2.1 KB)
    __shared__ float sh_m[2][LT];                   // masks (4 KB)

    // ---- stage masks ----
    for (int t = tid; t < LT; t += 512) {
        sh_m[0][t] = 1.f - (float)isini[(size_t)t * NB + n0];
        sh_m[1][t] = 1.f - (float)isini[(size_t)t * NB + n0 + 1];
    }

    // ---- B-frags: combined [Wih | Whh] row gate = gs*128+j, 8 K-chunks ----
    // (layout identical to the harness-verified round-1/2 kernels)
    f16x8 bfrag[4][8];
    float bs[4];
#pragma unroll
    for (int gs = 0; gs < 4; ++gs) {
        const int gate = gs * 128 + j;
        bs[gs] = bih[gate] + bhh[gate];
        const float4* wi = (const float4*)(Wih + (size_t)gate * DI);
        const float4* wh = (const float4*)(Whh + (size_t)gate * DH);
#pragma unroll
        for (int kc = 0; kc < 4; ++kc) {
            float4 a = wi[kc * 8 + quad * 2];
            float4 b = wi[kc * 8 + quad * 2 + 1];
            uint4 u;
            u.x = pack2(a.x, a.y); u.y = pack2(a.z, a.w);
            u.z = pack2(b.x, b.y); u.w = pack2(b.z, b.w);
            bfrag[gs][kc] = __builtin_bit_cast(f16x8, u);
        }
#pragma unroll
        for (int kc = 0; kc < 4; ++kc) {
            float4 a = wh[kc * 8 + quad * 2];
            float4 b = wh[kc * 8 + quad * 2 + 1];
            uint4 u;
            u.x = pack2(a.x, a.y); u.y = pack2(a.z, a.w);
            u.z = pack2(b.x, b.y); u.w = pack2(b.z, b.w);
            bfrag[gs][4 + kc] = __builtin_bit_cast(f16x8, u);
        }
    }

    // active lanes for state: quad 0 -> n0, quad 2 -> n1 (C row 0 / 8, reg 0)
    const bool act = (quad & 1) == 0;
    const int  nr  = quad >> 1;
    const int  n   = n0 + nr;

    float cval = 0.f, hval = 0.f, mcur = 0.f;
    if (act) {
        hval = hc0[(size_t)n * (2 * DH) + j];
        cval = hc0[(size_t)n * (2 * DH) + DH + j];
        mcur = 1.f - (float)isini[n];              // m(0)
        sh_a[0][nr][128 + j] = (f16)(hval * mcur); // masked h into A, k=128..255
    }

    // ---- x staging lanes: lane<8 of each wave covers 64 float4 = 2 rows ----
    const int  sflat = w * 8 + (lane & 7);   // 0..63
    const int  srow  = sflat >> 5;           // 0..1
    const int  sf4   = sflat & 31;           // float4 idx within row
    const bool sact  = (lane & 63) < 8;
    float4 xp = {0.f, 0.f, 0.f, 0.f};
    if (sact) {
        // x(0): stage directly
        const float4* sp0 = (const float4*)(x + ((size_t)0 * NB + n0 + srow) * DI);
        float4 v = sp0[sf4];
        uint2 u2;
        u2.x = pack2(v.x, v.y); u2.y = pack2(v.z, v.w);
        *(uint2*)&sh_a[0][srow][sf4 * 4] = u2;
        // x(1): prefetch into regs (written to LDS at step 0)
        const float4* sp1 = (const float4*)(x + ((size_t)1 * NB + n0 + srow) * DI);
        xp = sp1[sf4];
    }
    __syncthreads();

    const int rowsel = l16 >> 3;   // A rows 0-7 <- n0, 8-15 <- n1
    float* outp = out + (size_t)n * DH + j;

    for (int t = 0; t < LT; ++t) {
        const int buf  = t & 1;
        const int nbuf = buf ^ 1;

        // ---- A-frags for this step (broadcast reads, rows 8 banks apart) ----
        const uint4* ab = (const uint4*)&sh_a[buf][0][0];
        f16x8 af[8];
#pragma unroll
        for (int kc = 0; kc < 8; ++kc)
            af[kc] = __builtin_bit_cast(f16x8, ab[rowsel * ASTR + kc * 4 + quad]);

        // ---- x pipeline: write x(t+1) (loaded a full step ago), load x(t+2) ----
        if (sact) {
            uint2 u2;
            u2.x = pack2(xp.x, xp.y); u2.y = pack2(xp.z, xp.w);
            *(uint2*)&sh_a[nbuf][srow][sf4 * 4] = u2;
            int t2 = (t + 2 < LT) ? (t + 2) : (LT - 1);
            const float4* sp = (const float4*)(x + ((size_t)t2 * NB + n0 + srow) * DI);
            xp = sp[sf4];
        }

        // ---- 32 MFMA: 4 gate-slice chains x 8 K-chunks (K=256) ----
        floatx4 acc[4];
#pragma unroll
        for (int gs = 0; gs < 4; ++gs) acc[gs] = (floatx4){0.f, 0.f, 0.f, 0.f};
#pragma unroll
        for (int kc = 0; kc < 8; ++kc) {
#pragma unroll
            for (int gs = 0; gs < 4; ++gs)
                acc[gs] = __builtin_amdgcn_mfma_f32_16x16x32_f16(
                    af[kc], bfrag[gs][kc], acc[gs], 0, 0, 0);
        }

        // ---- lane-local nonlinearity (quads 0,2) ----
        if (act) {
            float ig = acc[0][0] + bs[0];
            float fg = acc[1][0] + bs[1];
            float gg = acc[2][0] + bs[2];
            float og = acc[3][0] + bs[3];
            float cc = sigm(fg) * (mcur * cval) + sigm(ig) * tanh_(gg);
            hval = sigm(og) * tanh_(cc);
            cval = cc;
            outp[(size_t)t * (NB * DH)] = hval;
            int t1 = (t + 1 < LT) ? (t + 1) : (LT - 1);
            float mn = sh_m[nr][t1];
            sh_a[nbuf][nr][128 + j] = (f16)(hval * mn);  // masked h for step t+1
            mcur = mn;
        }
        __syncthreads();   // single barrier per step
    }

    if (act) {
        size_t base = (size_t)LT * NB * DH;
        out[base + (size_t)n * (2 * DH) + j]      = hval;
        out[base + (size_t)n * (2 * DH) + DH + j] = cval;
    }
}

extern "C" void kernel_launch(void* const* d_in, const int* in_sizes, int n_in,
                              void* d_out, int out_size, void* d_ws, size_t ws_size,
                              hipStream_t stream) {
    const float* x     = (const float*)d_in[0];
    const float* hc0   = (const float*)d_in[1];
    const int*   isini = (const int*)d_in[2];
    const float* Wih   = (const float*)d_in[3];
    const float* Whh   = (const float*)d_in[4];
    const float* bih   = (const float*)d_in[5];
    const float* bhh   = (const float*)d_in[6];
    float* out = (float*)d_out;

    lstm_fused_mfma<<<dim3(NB / 2), dim3(512), 0, stream>>>(
        x, hc0, isini, Wih, Whh, bih, bhh, out);
}